// Round 8
// baseline (171.459 us; speedup 1.0000x reference)
//
#include <hip/hip_runtime.h>
#include <math.h>

#define NB   512
#define NPM  8
#define NPH  16
#define NNM  64
#define NNH  64
#define ND   2048
#define TEMP_INV 14.285714285714285714f
#define POSM 0.1f
#define NEGM 0.1f

static constexpr int ROWS_PER_B = NPM + NPH + NNM + NNH;  // 152
static constexpr int WPB        = 8;                      // waves per b
static constexpr int NRW        = ROWS_PER_B / WPB;       // 19 rows per wave

typedef __attribute__((ext_vector_type(8))) short bf16x8;
typedef __attribute__((ext_vector_type(4))) float f32x4;

// round-to-nearest-even f32 -> bf16 bits
__device__ __forceinline__ unsigned short f2bf(float f) {
  unsigned int u = __float_as_uint(f);
  return (unsigned short)((u + 0x7FFFu + ((u >> 16) & 1u)) >> 16);
}

__device__ __forceinline__ void acc_ss_dot(const float4 v, const float4 u,
                                           float& ss, float& dot) {
  ss  = fmaf(v.x, v.x, ss);  ss  = fmaf(v.y, v.y, ss);
  ss  = fmaf(v.z, v.z, ss);  ss  = fmaf(v.w, v.w, ss);
  dot = fmaf(v.x, u.x, dot); dot = fmaf(v.y, u.y, dot);
  dot = fmaf(v.z, u.z, dot); dot = fmaf(v.w, u.w, dot);
}

__device__ __forceinline__ void block_reduce2(float& a, float& b) {
#pragma unroll
  for (int off = 32; off > 0; off >>= 1) {
    a += __shfl_down(a, off);
    b += __shfl_down(b, off);
  }
  __shared__ float sa[4], sb[4];
  const int w = threadIdx.x >> 6;
  if ((threadIdx.x & 63) == 0) { sa[w] = a; sb[w] = b; }
  __syncthreads();
  a = sa[0] + sa[1] + sa[2] + sa[3];
  b = sb[0] + sb[1] + sb[2] + sb[3];
  __syncthreads();
}

// async global->LDS, 16 B per lane per issue (fire-and-forget, no dest VGPRs)
__device__ __forceinline__ void gl_lds16(const float* g, float* l) {
  __builtin_amdgcn_global_load_lds(
      (const __attribute__((address_space(1))) unsigned int*)g,
      (__attribute__((address_space(3))) unsigned int*)l, 16, 0, 0);
}

#define VMWAIT(N) asm volatile("s_waitcnt vmcnt(" #N ")" ::: "memory")
#define ROT3()    { float* t_ = s0; s0 = s1; s1 = s2; s2 = t_; }

// ---- k_prep: q_norm (f32 + bf16), pf_norm (bf16), anchor, zero accumulators --
__global__ __launch_bounds__(256) void k_prep(const float* __restrict__ q,
                                              const float* __restrict__ pm,
                                              float* __restrict__ qn,
                                              unsigned short* __restrict__ qb,
                                              unsigned short* __restrict__ pb,
                                              float* __restrict__ anchor,
                                              float* __restrict__ pos,
                                              float* __restrict__ neg) {
  const int b = blockIdx.x;
  const int t = threadIdx.x;

  const float4* qrow = (const float4*)(q + (size_t)b * ND);
  float4 q0 = qrow[t];
  float4 q1 = qrow[t + 256];
  float ss = 0.f, dummy = 0.f;
  ss = fmaf(q0.x, q0.x, ss); ss = fmaf(q0.y, q0.y, ss);
  ss = fmaf(q0.z, q0.z, ss); ss = fmaf(q0.w, q0.w, ss);
  ss = fmaf(q1.x, q1.x, ss); ss = fmaf(q1.y, q1.y, ss);
  ss = fmaf(q1.z, q1.z, ss); ss = fmaf(q1.w, q1.w, ss);
  block_reduce2(ss, dummy);
  const float qinv = 1.0f / fmaxf(sqrtf(ss), 1e-8f);
  q0.x *= qinv; q0.y *= qinv; q0.z *= qinv; q0.w *= qinv;
  q1.x *= qinv; q1.y *= qinv; q1.z *= qinv; q1.w *= qinv;
  float4* qno = (float4*)(qn + (size_t)b * ND);
  qno[t] = q0; qno[t + 256] = q1;
  ushort4* qbo = (ushort4*)(qb + (size_t)b * ND);
  ushort4 qc0, qc1;
  qc0.x = f2bf(q0.x); qc0.y = f2bf(q0.y); qc0.z = f2bf(q0.z); qc0.w = f2bf(q0.w);
  qc1.x = f2bf(q1.x); qc1.y = f2bf(q1.y); qc1.z = f2bf(q1.z); qc1.w = f2bf(q1.w);
  qbo[t] = qc0; qbo[t + 256] = qc1;

  const float4* prow = (const float4*)(pm + (size_t)b * NPM * ND);
  float4 p0 = prow[t];
  float4 p1 = prow[t + 256];
  float pss = 0.f, dot = 0.f;
  acc_ss_dot(p0, q0, pss, dot);
  acc_ss_dot(p1, q1, pss, dot);
  block_reduce2(pss, dot);
  const float pinv = 1.0f / fmaxf(sqrtf(pss), 1e-8f);
  p0.x *= pinv; p0.y *= pinv; p0.z *= pinv; p0.w *= pinv;
  p1.x *= pinv; p1.y *= pinv; p1.z *= pinv; p1.w *= pinv;
  ushort4* pbo = (ushort4*)(pb + (size_t)b * ND);
  ushort4 pc0, pc1;
  pc0.x = f2bf(p0.x); pc0.y = f2bf(p0.y); pc0.z = f2bf(p0.z); pc0.w = f2bf(p0.w);
  pc1.x = f2bf(p1.x); pc1.y = f2bf(p1.y); pc1.z = f2bf(p1.z); pc1.w = f2bf(p1.w);
  pbo[t] = pc0; pbo[t + 256] = pc1;

  if (t == 0) {
    anchor[b] = dot * pinv;
    pos[b] = 0.f;
    neg[b] = 0.f;
  }
}

// ---- k_rows: persistent waves; 3-slot 4KB-chunk DMA pipeline -----------------
// Each wave: 19 rows = 38 half-row chunks of 4KB. 3 private LDS slots; steady
// state keeps 2 chunks (8 DMA issues) in flight via counted vmcnt(8); a slot
// is restaged immediately after its inline-asm ds_read block (which carries
// its own lgkmcnt(0), invisible to the compiler's waitcnt pass). 48KB/block
// -> 3 blocks/CU = 12 waves/CU. No __syncthreads anywhere.
__global__ __launch_bounds__(256, 3) void k_rows(const float* __restrict__ pmain,
                                                 const float* __restrict__ phard,
                                                 const float* __restrict__ nmain,
                                                 const float* __restrict__ nhard,
                                                 const float* __restrict__ qn,
                                                 const float* __restrict__ anchor,
                                                 float* __restrict__ pos,
                                                 float* __restrict__ neg) {
  __shared__ float lds[4][3][1024];  // 48 KB: [wave][slot][chunk]

  const int wid    = threadIdx.x >> 6;
  const int lane   = threadIdx.x & 63;
  const int wgl    = blockIdx.x * 4 + wid;   // 0..4095
  const int b      = wgl >> 3;               // 0..511
  const int wslice = wgl & 7;                // 0..7

  // row k (0..18) -> per-lane global base pointer (row index wslice + 8k)
  auto rowbase = [&](int k) -> const float* {
    const int r = wslice + WPB * k;          // < 152 always
    const float* p;
    if (r < NPM)                  p = pmain + ((size_t)b * NPM + r) * ND;
    else if (r < NPM + NPH)       p = phard + ((size_t)b * NPH + (r - NPM)) * ND;
    else if (r < NPM + NPH + NNM) p = nmain + ((size_t)b * NNM + (r - NPM - NPH)) * ND;
    else                          p = nhard + ((size_t)b * NNH + (r - NPM - NPH - NNM)) * ND;
    return p + lane * 4;
  };

  // stage chunk c (row c>>1, half c&1): 4 async DMA issues of 1 KB
  auto stage = [&](int c, float* slot) {
    const float* g = rowbase(c >> 1) + (c & 1) * 1024;
#pragma unroll
    for (int j = 0; j < 4; j++) gl_lds16(g + j * 256, slot + j * 256);
  };

  // read one 4KB chunk from a slot: inline-asm ds_read_b128 x4 with in-asm
  // lgkmcnt(0); "memory" clobber stops the next stage() hoisting above it.
  auto lread = [&](const float* slot, float4& A, float4& B, float4& C, float4& D) {
    const __attribute__((address_space(3))) char* ls =
        (const __attribute__((address_space(3))) char*)slot + lane * 16;
    asm volatile("ds_read_b128 %0, %4\n\t"
                 "ds_read_b128 %1, %4 offset:1024\n\t"
                 "ds_read_b128 %2, %4 offset:2048\n\t"
                 "ds_read_b128 %3, %4 offset:3072\n\t"
                 "s_waitcnt lgkmcnt(0)"
                 : "=&v"(A), "=&v"(B), "=&v"(C), "=&v"(D)
                 : "v"(ls)
                 : "memory");
    __builtin_amdgcn_sched_barrier(0);
  };

  // q-hat hoisted to registers (L2-resident, once per wave)
  const float4* qrow = (const float4*)(qn + (size_t)b * ND);
  const float4 u0 = qrow[lane + 64 * 0], u1 = qrow[lane + 64 * 1];
  const float4 u2 = qrow[lane + 64 * 2], u3 = qrow[lane + 64 * 3];
  const float4 u4 = qrow[lane + 64 * 4], u5 = qrow[lane + 64 * 5];
  const float4 u6 = qrow[lane + 64 * 6], u7 = qrow[lane + 64 * 7];
  const float anc = anchor[b];

  float pacc = 0.f, nacc = 0.f;

  auto finalize = [&](float ssv, float dtv, int r) {
#pragma unroll
    for (int off = 32; off > 0; off >>= 1) {
      ssv += __shfl_xor(ssv, off);
      dtv += __shfl_xor(dtv, off);
    }
    const float sim = dtv * rsqrtf(fmaxf(ssv, 1e-16f));
    const float e   = __expf(sim * TEMP_INV);
    if (r < NPM) {
      pacc += e;
    } else if (r < NPM + NPH) {
      if (sim >= anc - POSM) pacc += e;
    } else {
      if (sim <= anc + NEGM) nacc += e;
    }
  };

  float* s0 = &lds[wid][0][0];
  float* s1 = &lds[wid][1][0];
  float* s2 = &lds[wid][2][0];

  stage(0, s0); stage(1, s1); stage(2, s2);   // 12 issues in flight

  float4 A, B, C, D;
  for (int k = 0; k < 17; ++k) {              // rows 0..16, chunks 2k / 2k+1
    float sa = 0.f, sb = 0.f, da = 0.f, db = 0.f;
    VMWAIT(8);                                // chunk 2k ready; 2 in flight
    lread(s0, A, B, C, D);
    stage(2 * k + 3, s0);                     // refill freed slot (<= 36)
    ROT3();
    acc_ss_dot(A, u0, sa, da); acc_ss_dot(B, u1, sb, db);
    acc_ss_dot(C, u2, sa, da); acc_ss_dot(D, u3, sb, db);
    VMWAIT(8);                                // chunk 2k+1 ready
    lread(s0, A, B, C, D);
    stage(2 * k + 4, s0);                     // <= 36 for k<=16
    ROT3();
    acc_ss_dot(A, u4, sa, da); acc_ss_dot(B, u5, sb, db);
    acc_ss_dot(C, u6, sa, da); acc_ss_dot(D, u7, sb, db);
    finalize(sa + sb, da + db, wslice + WPB * k);
  }
  {  // row 17: chunks 34, 35; stage the final chunk 37
    float sa = 0.f, sb = 0.f, da = 0.f, db = 0.f;
    VMWAIT(8);
    lread(s0, A, B, C, D);
    stage(37, s0);
    ROT3();
    acc_ss_dot(A, u0, sa, da); acc_ss_dot(B, u1, sb, db);
    acc_ss_dot(C, u2, sa, da); acc_ss_dot(D, u3, sb, db);
    VMWAIT(8);
    lread(s0, A, B, C, D);
    ROT3();
    acc_ss_dot(A, u4, sa, da); acc_ss_dot(B, u5, sb, db);
    acc_ss_dot(C, u6, sa, da); acc_ss_dot(D, u7, sb, db);
    finalize(sa + sb, da + db, wslice + WPB * 17);
  }
  {  // row 18: chunks 36, 37; drain to vmcnt(0) before wave exit
    float sa = 0.f, sb = 0.f, da = 0.f, db = 0.f;
    VMWAIT(4);
    lread(s0, A, B, C, D);
    ROT3();
    acc_ss_dot(A, u0, sa, da); acc_ss_dot(B, u1, sb, db);
    acc_ss_dot(C, u2, sa, da); acc_ss_dot(D, u3, sb, db);
    VMWAIT(0);
    lread(s0, A, B, C, D);
    acc_ss_dot(A, u4, sa, da); acc_ss_dot(B, u5, sb, db);
    acc_ss_dot(C, u6, sa, da); acc_ss_dot(D, u7, sb, db);
    finalize(sa + sb, da + db, wslice + WPB * 18);
  }

  if (lane == 0) {
    if (pacc != 0.f) atomicAdd(pos + b, pacc);
    if (nacc != 0.f) atomicAdd(neg + b, nacc);
  }
}

// ---- k_sim: three 512x512 sim matrices via bf16 MFMA, masked exp row-sums ----
__global__ __launch_bounds__(256) void k_sim(const unsigned short* __restrict__ qb,
                                             const unsigned short* __restrict__ pb,
                                             const float* __restrict__ anchor,
                                             float* __restrict__ neg) {
  const int z = blockIdx.z;
  const unsigned short* __restrict__ A = (z == 1) ? pb : qb;
  const unsigned short* __restrict__ B = (z == 0) ? qb : pb;

  const int wid  = blockIdx.x * 4 + (threadIdx.x >> 6);  // 0..511
  const int m    = wid >> 4;   // row-tile 0..31
  const int n2   = wid & 15;   // col-pair 0..15
  const int lane = threadIdx.x & 63;
  const int r16  = lane & 15;
  const int kc   = lane >> 4;

  const size_t abase  = ((size_t)(m * 16 + r16)) * ND + kc * 8;
  const size_t b0base = ((size_t)(n2 * 32 + r16)) * ND + kc * 8;
  const size_t b1base = b0base + (size_t)16 * ND;

  f32x4 acc0 = {0.f, 0.f, 0.f, 0.f};
  f32x4 acc1 = {0.f, 0.f, 0.f, 0.f};
#pragma unroll 2
  for (int k0 = 0; k0 < ND; k0 += 64) {
    const bf16x8 a0  = *(const bf16x8*)(A + abase  + k0);
    const bf16x8 a1  = *(const bf16x8*)(A + abase  + k0 + 32);
    const bf16x8 b00 = *(const bf16x8*)(B + b0base + k0);
    const bf16x8 b10 = *(const bf16x8*)(B + b1base + k0);
    const bf16x8 b01 = *(const bf16x8*)(B + b0base + k0 + 32);
    const bf16x8 b11 = *(const bf16x8*)(B + b1base + k0 + 32);
    acc0 = __builtin_amdgcn_mfma_f32_16x16x32_bf16(a0, b00, acc0, 0, 0, 0);
    acc1 = __builtin_amdgcn_mfma_f32_16x16x32_bf16(a0, b10, acc1, 0, 0, 0);
    acc0 = __builtin_amdgcn_mfma_f32_16x16x32_bf16(a1, b01, acc0, 0, 0, 0);
    acc1 = __builtin_amdgcn_mfma_f32_16x16x32_bf16(a1, b11, acc1, 0, 0, 0);
  }

  const int rbase = m * 16 + kc * 4;
  const int gc0   = n2 * 32 + r16;
#pragma unroll
  for (int j = 0; j < 4; j++) {
    const int gr = rbase + j;
    const float thr = anchor[gr] + NEGM;
    float s = 0.f;
    const float v0 = acc0[j];
    const float v1 = acc1[j];
    if (gr != gc0      && v0 <= thr) s += expf(v0 * TEMP_INV);
    if (gr != gc0 + 16 && v1 <= thr) s += expf(v1 * TEMP_INV);
    s += __shfl_xor(s, 1);
    s += __shfl_xor(s, 2);
    s += __shfl_xor(s, 4);
    s += __shfl_xor(s, 8);
    if (r16 == 0) atomicAdd(neg + gr, s);
  }
}

// ---- k_loss: per-b loss, mean ------------------------------------------------
__global__ __launch_bounds__(512) void k_loss(const float* __restrict__ pos,
                                              const float* __restrict__ neg,
                                              float* __restrict__ out) {
  const int t = threadIdx.x;
  const float p = pos[t];
  const float n = neg[t];
  float l = -logf(p / (p + n + 1e-8f));
#pragma unroll
  for (int off = 32; off > 0; off >>= 1) l += __shfl_down(l, off);
  __shared__ float s[8];
  if ((t & 63) == 0) s[t >> 6] = l;
  __syncthreads();
  if (t == 0) {
    float tot = 0.f;
#pragma unroll
    for (int i = 0; i < 8; i++) tot += s[i];
    out[0] = tot / (float)NB;
  }
}

extern "C" void kernel_launch(void* const* d_in, const int* in_sizes, int n_in,
                              void* d_out, int out_size, void* d_ws, size_t ws_size,
                              hipStream_t stream) {
  const float* q  = (const float*)d_in[0];
  const float* pm = (const float*)d_in[1];
  const float* ph = (const float*)d_in[2];
  const float* nm = (const float*)d_in[3];
  const float* nh = (const float*)d_in[4];
  float* out = (float*)d_out;

  float* ws = (float*)d_ws;
  float*          qn     = ws;                                  // 512*2048 f32 (4 MB)
  unsigned short* qb     = (unsigned short*)(ws + (size_t)NB * ND);        // 2 MB
  unsigned short* pb     = qb + (size_t)NB * ND;                           // 2 MB
  float*          anchor = (float*)(pb + (size_t)NB * ND);      // 512
  float*          pos    = anchor + NB;                         // 512
  float*          neg    = pos + NB;                            // 512

  k_prep<<<NB, 256, 0, stream>>>(q, pm, qn, qb, pb, anchor, pos, neg);
  k_rows<<<(NB * WPB) / 4, 256, 0, stream>>>(pm, ph, nm, nh, qn, anchor, pos, neg);
  k_sim<<<dim3(128, 1, 3), 256, 0, stream>>>(qb, pb, anchor, neg);
  k_loss<<<1, 512, 0, stream>>>(pos, neg, out);
}

// Round 9
// 171.349 us; speedup vs baseline: 1.0006x; 1.0006x over previous
//
#include <hip/hip_runtime.h>
#include <math.h>

#define NB   512
#define NPM  8
#define NPH  16
#define NNM  64
#define NNH  64
#define ND   2048
#define TEMP_INV 14.285714285714285714f
#define POSM 0.1f
#define NEGM 0.1f

static constexpr int ROWS_PER_B = NPM + NPH + NNM + NNH;  // 152
static constexpr int WPB        = 8;                      // waves per b
static constexpr int NRW        = ROWS_PER_B / WPB;       // 19 rows per wave
static constexpr int NBLK_ROWS  = NB * WPB / 4;           // 1024 row-blocks
static constexpr int NBLK_SIM   = 384;                    // 128 x 3 sim-blocks

typedef __attribute__((ext_vector_type(8))) short bf16x8;
typedef __attribute__((ext_vector_type(4))) float f32x4;

__device__ __forceinline__ unsigned short f2bf(float f) {
  unsigned int u = __float_as_uint(f);
  return (unsigned short)((u + 0x7FFFu + ((u >> 16) & 1u)) >> 16);
}

__device__ __forceinline__ void acc_ss_dot(const float4 v, const float4 u,
                                           float& ss, float& dot) {
  ss  = fmaf(v.x, v.x, ss);  ss  = fmaf(v.y, v.y, ss);
  ss  = fmaf(v.z, v.z, ss);  ss  = fmaf(v.w, v.w, ss);
  dot = fmaf(v.x, u.x, dot); dot = fmaf(v.y, u.y, dot);
  dot = fmaf(v.z, u.z, dot); dot = fmaf(v.w, u.w, dot);
}

__device__ __forceinline__ void block_reduce2(float& a, float& b) {
#pragma unroll
  for (int off = 32; off > 0; off >>= 1) {
    a += __shfl_down(a, off);
    b += __shfl_down(b, off);
  }
  __shared__ float sa[4], sb[4];
  const int w = threadIdx.x >> 6;
  if ((threadIdx.x & 63) == 0) { sa[w] = a; sb[w] = b; }
  __syncthreads();
  a = sa[0] + sa[1] + sa[2] + sa[3];
  b = sb[0] + sb[1] + sb[2] + sb[3];
  __syncthreads();
}

// async global->LDS, 16 B per lane per issue (fire-and-forget)
__device__ __forceinline__ void gl_lds16(const float* g, float* l) {
  __builtin_amdgcn_global_load_lds(
      (const __attribute__((address_space(1))) unsigned int*)g,
      (__attribute__((address_space(3))) unsigned int*)l, 16, 0, 0);
}

#define VMWAIT(N) asm volatile("s_waitcnt vmcnt(" #N ")" ::: "memory")
#define ROT3()    { float* t_ = s0; s0 = s1; s1 = s2; s2 = t_; }

// ---- k_prep: q_norm (f32 + bf16), pf_norm (bf16), anchor, zero accumulators --
__global__ __launch_bounds__(256) void k_prep(const float* __restrict__ q,
                                              const float* __restrict__ pm,
                                              float* __restrict__ qn,
                                              unsigned short* __restrict__ qb,
                                              unsigned short* __restrict__ pb,
                                              float* __restrict__ anchor,
                                              float* __restrict__ pos,
                                              float* __restrict__ neg) {
  const int b = blockIdx.x;
  const int t = threadIdx.x;

  const float4* qrow = (const float4*)(q + (size_t)b * ND);
  float4 q0 = qrow[t];
  float4 q1 = qrow[t + 256];
  float ss = 0.f, dummy = 0.f;
  ss = fmaf(q0.x, q0.x, ss); ss = fmaf(q0.y, q0.y, ss);
  ss = fmaf(q0.z, q0.z, ss); ss = fmaf(q0.w, q0.w, ss);
  ss = fmaf(q1.x, q1.x, ss); ss = fmaf(q1.y, q1.y, ss);
  ss = fmaf(q1.z, q1.z, ss); ss = fmaf(q1.w, q1.w, ss);
  block_reduce2(ss, dummy);
  const float qinv = 1.0f / fmaxf(sqrtf(ss), 1e-8f);
  q0.x *= qinv; q0.y *= qinv; q0.z *= qinv; q0.w *= qinv;
  q1.x *= qinv; q1.y *= qinv; q1.z *= qinv; q1.w *= qinv;
  float4* qno = (float4*)(qn + (size_t)b * ND);
  qno[t] = q0; qno[t + 256] = q1;
  ushort4* qbo = (ushort4*)(qb + (size_t)b * ND);
  ushort4 qc0, qc1;
  qc0.x = f2bf(q0.x); qc0.y = f2bf(q0.y); qc0.z = f2bf(q0.z); qc0.w = f2bf(q0.w);
  qc1.x = f2bf(q1.x); qc1.y = f2bf(q1.y); qc1.z = f2bf(q1.z); qc1.w = f2bf(q1.w);
  qbo[t] = qc0; qbo[t + 256] = qc1;

  const float4* prow = (const float4*)(pm + (size_t)b * NPM * ND);
  float4 p0 = prow[t];
  float4 p1 = prow[t + 256];
  float pss = 0.f, dot = 0.f;
  acc_ss_dot(p0, q0, pss, dot);
  acc_ss_dot(p1, q1, pss, dot);
  block_reduce2(pss, dot);
  const float pinv = 1.0f / fmaxf(sqrtf(pss), 1e-8f);
  p0.x *= pinv; p0.y *= pinv; p0.z *= pinv; p0.w *= pinv;
  p1.x *= pinv; p1.y *= pinv; p1.z *= pinv; p1.w *= pinv;
  ushort4* pbo = (ushort4*)(pb + (size_t)b * ND);
  ushort4 pc0, pc1;
  pc0.x = f2bf(p0.x); pc0.y = f2bf(p0.y); pc0.z = f2bf(p0.z); pc0.w = f2bf(p0.w);
  pc1.x = f2bf(p1.x); pc1.y = f2bf(p1.y); pc1.z = f2bf(p1.z); pc1.w = f2bf(p1.w);
  pbo[t] = pc0; pbo[t + 256] = pc1;

  if (t == 0) {
    anchor[b] = dot * pinv;
    pos[b] = 0.f;
    neg[b] = 0.f;
  }
}

// ---- fused k_main: row-blocks (0..1023) + sim-blocks (1024..1407) ------------
// Row part: 2KB chunks, 3 slots/wave, 24KB/block -> 6 blocks/CU = 24 waves/CU
// = 24 concurrent row-streams per CU. Counted vmcnt keeps 2 chunks (4 issues)
// in flight per wave; full drain only at the end.
__global__ __launch_bounds__(256, 6) void k_main(const float* __restrict__ pmain,
                                                 const float* __restrict__ phard,
                                                 const float* __restrict__ nmain,
                                                 const float* __restrict__ nhard,
                                                 const float* __restrict__ qn,
                                                 const unsigned short* __restrict__ qb,
                                                 const unsigned short* __restrict__ pb,
                                                 const float* __restrict__ anchor,
                                                 float* __restrict__ pos,
                                                 float* __restrict__ neg) {
  __shared__ float lds[4][3][512];  // 24 KB: [wave][slot][2KB chunk]

  if (blockIdx.x >= NBLK_ROWS) {
    // ---------------- sim branch: three 512x512 bf16-MFMA sim matrices -------
    const int sblk = blockIdx.x - NBLK_ROWS;   // 0..383
    const int z    = sblk >> 7;                // 0..2
    const int xb   = sblk & 127;               // 0..127
    const unsigned short* __restrict__ A = (z == 1) ? pb : qb;
    const unsigned short* __restrict__ B = (z == 0) ? qb : pb;

    const int wid  = xb * 4 + (threadIdx.x >> 6);  // 0..511
    const int m    = wid >> 4;
    const int n2   = wid & 15;
    const int lane = threadIdx.x & 63;
    const int r16  = lane & 15;
    const int kc   = lane >> 4;

    const size_t abase  = ((size_t)(m * 16 + r16)) * ND + kc * 8;
    const size_t b0base = ((size_t)(n2 * 32 + r16)) * ND + kc * 8;
    const size_t b1base = b0base + (size_t)16 * ND;

    f32x4 acc0 = {0.f, 0.f, 0.f, 0.f};
    f32x4 acc1 = {0.f, 0.f, 0.f, 0.f};
#pragma unroll 2
    for (int k0 = 0; k0 < ND; k0 += 64) {
      const bf16x8 a0  = *(const bf16x8*)(A + abase  + k0);
      const bf16x8 a1  = *(const bf16x8*)(A + abase  + k0 + 32);
      const bf16x8 b00 = *(const bf16x8*)(B + b0base + k0);
      const bf16x8 b10 = *(const bf16x8*)(B + b1base + k0);
      const bf16x8 b01 = *(const bf16x8*)(B + b0base + k0 + 32);
      const bf16x8 b11 = *(const bf16x8*)(B + b1base + k0 + 32);
      acc0 = __builtin_amdgcn_mfma_f32_16x16x32_bf16(a0, b00, acc0, 0, 0, 0);
      acc1 = __builtin_amdgcn_mfma_f32_16x16x32_bf16(a0, b10, acc1, 0, 0, 0);
      acc0 = __builtin_amdgcn_mfma_f32_16x16x32_bf16(a1, b01, acc0, 0, 0, 0);
      acc1 = __builtin_amdgcn_mfma_f32_16x16x32_bf16(a1, b11, acc1, 0, 0, 0);
    }

    const int rbase = m * 16 + kc * 4;
    const int gc0   = n2 * 32 + r16;
#pragma unroll
    for (int j = 0; j < 4; j++) {
      const int gr = rbase + j;
      const float thr = anchor[gr] + NEGM;
      float s = 0.f;
      const float v0 = acc0[j];
      const float v1 = acc1[j];
      if (gr != gc0      && v0 <= thr) s += expf(v0 * TEMP_INV);
      if (gr != gc0 + 16 && v1 <= thr) s += expf(v1 * TEMP_INV);
      s += __shfl_xor(s, 1);
      s += __shfl_xor(s, 2);
      s += __shfl_xor(s, 4);
      s += __shfl_xor(s, 8);
      if (r16 == 0) atomicAdd(neg + gr, s);
    }
    return;
  }

  // ---------------- row branch ------------------------------------------------
  const int wid    = threadIdx.x >> 6;
  const int lane   = threadIdx.x & 63;
  const int wgl    = blockIdx.x * 4 + wid;   // 0..4095
  const int b      = wgl >> 3;               // 0..511
  const int wslice = wgl & 7;                // 0..7

  auto rowbase = [&](int k) -> const float* {
    const int r = wslice + WPB * k;          // < 152 always
    const float* p;
    if (r < NPM)                  p = pmain + ((size_t)b * NPM + r) * ND;
    else if (r < NPM + NPH)       p = phard + ((size_t)b * NPH + (r - NPM)) * ND;
    else if (r < NPM + NPH + NNM) p = nmain + ((size_t)b * NNM + (r - NPM - NPH)) * ND;
    else                          p = nhard + ((size_t)b * NNH + (r - NPM - NPH - NNM)) * ND;
    return p + lane * 4;
  };

  // stage 2KB chunk c (row c>>2, quarter c&3): 2 async DMA issues of 1 KB
  auto stage = [&](int c, float* slot) {
    const float* g = rowbase(c >> 2) + (c & 3) * 512;
    gl_lds16(g, slot);
    gl_lds16(g + 256, slot + 256);
  };

  // read one 2KB chunk: 2x ds_read_b128 + in-asm lgkmcnt(0)
  auto lread2 = [&](const float* slot, float4& A, float4& B) {
    const __attribute__((address_space(3))) char* ls =
        (const __attribute__((address_space(3))) char*)slot + lane * 16;
    asm volatile("ds_read_b128 %0, %2\n\t"
                 "ds_read_b128 %1, %2 offset:1024\n\t"
                 "s_waitcnt lgkmcnt(0)"
                 : "=&v"(A), "=&v"(B)
                 : "v"(ls)
                 : "memory");
    __builtin_amdgcn_sched_barrier(0);
  };

  // q-hat hoisted to registers (L2-resident, once per wave)
  const float4* qrow = (const float4*)(qn + (size_t)b * ND);
  float4 u[8];
#pragma unroll
  for (int j = 0; j < 8; j++) u[j] = qrow[lane + 64 * j];
  const float anc = anchor[b];
  // drain prologue loads so the loop's vmcnt counting is exact
  asm volatile("s_waitcnt vmcnt(0)" ::: "memory");

  float pacc = 0.f, nacc = 0.f;

  auto finalize = [&](float ssv, float dtv, int r) {
#pragma unroll
    for (int off = 32; off > 0; off >>= 1) {
      ssv += __shfl_xor(ssv, off);
      dtv += __shfl_xor(dtv, off);
    }
    const float sim = dtv * rsqrtf(fmaxf(ssv, 1e-16f));
    const float e   = __expf(sim * TEMP_INV);
    if (r < NPM) {
      pacc += e;
    } else if (r < NPM + NPH) {
      if (sim >= anc - POSM) pacc += e;
    } else {
      if (sim <= anc + NEGM) nacc += e;
    }
  };

  float* s0 = &lds[wid][0][0];
  float* s1 = &lds[wid][1][0];
  float* s2 = &lds[wid][2][0];

  stage(0, s0); stage(1, s1); stage(2, s2);   // 6 issues in flight

  float4 A, B;
  for (int k = 0; k < 18; ++k) {              // rows 0..17, chunks 4k..4k+3
    float sa = 0.f, sb = 0.f, da = 0.f, db = 0.f;
#pragma unroll
    for (int j = 0; j < 4; ++j) {
      VMWAIT(4);                              // chunk 4k+j ready; 2 in flight
      lread2(s0, A, B);
      stage(4 * k + j + 3, s0);               // refill (max index 74 < 76)
      ROT3();
      acc_ss_dot(A, u[2 * j],     sa, da);
      acc_ss_dot(B, u[2 * j + 1], sb, db);
    }
    finalize(sa + sb, da + db, wslice + WPB * k);
  }
  {  // row 18: chunks 72..75; stage 75 then drain
    float sa = 0.f, sb = 0.f, da = 0.f, db = 0.f;
    VMWAIT(4); lread2(s0, A, B); stage(75, s0); ROT3();
    acc_ss_dot(A, u[0], sa, da); acc_ss_dot(B, u[1], sb, db);
    VMWAIT(4); lread2(s0, A, B); ROT3();
    acc_ss_dot(A, u[2], sa, da); acc_ss_dot(B, u[3], sb, db);
    VMWAIT(2); lread2(s0, A, B); ROT3();
    acc_ss_dot(A, u[4], sa, da); acc_ss_dot(B, u[5], sb, db);
    VMWAIT(0); lread2(s0, A, B);
    acc_ss_dot(A, u[6], sa, da); acc_ss_dot(B, u[7], sb, db);
    finalize(sa + sb, da + db, wslice + WPB * 18);
  }

  if (lane == 0) {
    if (pacc != 0.f) atomicAdd(pos + b, pacc);
    if (nacc != 0.f) atomicAdd(neg + b, nacc);
  }
}

// ---- k_loss: per-b loss, mean ------------------------------------------------
__global__ __launch_bounds__(512) void k_loss(const float* __restrict__ pos,
                                              const float* __restrict__ neg,
                                              float* __restrict__ out) {
  const int t = threadIdx.x;
  const float p = pos[t];
  const float n = neg[t];
  float l = -logf(p / (p + n + 1e-8f));
#pragma unroll
  for (int off = 32; off > 0; off >>= 1) l += __shfl_down(l, off);
  __shared__ float s[8];
  if ((t & 63) == 0) s[t >> 6] = l;
  __syncthreads();
  if (t == 0) {
    float tot = 0.f;
#pragma unroll
    for (int i = 0; i < 8; i++) tot += s[i];
    out[0] = tot / (float)NB;
  }
}

extern "C" void kernel_launch(void* const* d_in, const int* in_sizes, int n_in,
                              void* d_out, int out_size, void* d_ws, size_t ws_size,
                              hipStream_t stream) {
  const float* q  = (const float*)d_in[0];
  const float* pm = (const float*)d_in[1];
  const float* ph = (const float*)d_in[2];
  const float* nm = (const float*)d_in[3];
  const float* nh = (const float*)d_in[4];
  float* out = (float*)d_out;

  float* ws = (float*)d_ws;
  float*          qn     = ws;                                  // 512*2048 f32 (4 MB)
  unsigned short* qb     = (unsigned short*)(ws + (size_t)NB * ND);        // 2 MB
  unsigned short* pb     = qb + (size_t)NB * ND;                           // 2 MB
  float*          anchor = (float*)(pb + (size_t)NB * ND);      // 512
  float*          pos    = anchor + NB;                         // 512
  float*          neg    = pos + NB;                            // 512

  k_prep<<<NB, 256, 0, stream>>>(q, pm, qn, qb, pb, anchor, pos, neg);
  k_main<<<NBLK_ROWS + NBLK_SIM, 256, 0, stream>>>(pm, ph, nm, nh, qn, qb, pb,
                                                   anchor, pos, neg);
  k_loss<<<1, 512, 0, stream>>>(pos, neg, out);
}